// Round 1
// baseline (634.594 us; speedup 1.0000x reference)
//
#include <hip/hip_runtime.h>

typedef __bf16 bf16x8 __attribute__((ext_vector_type(8)));
typedef float f32x4 __attribute__((ext_vector_type(4)));
typedef unsigned short u16x8 __attribute__((ext_vector_type(8)));

__device__ __forceinline__ unsigned short f2bf(float f) {
  unsigned int u = __builtin_bit_cast(unsigned int, f);
  u += 0x7FFFu + ((u >> 16) & 1u);           // round-to-nearest-even
  return (unsigned short)(u >> 16);
}

// ---------------------------------------------------------------------------
// GEMM: out[m][n] = sum_k A[m][k] * B[n][k]
// A: f32 or bf16 [M][K] row-major; B: f32 [N][K] row-major (K-contiguous);
// out: bf16 or f32 [M][N]. Tile 128x128, BK=64, 256 thr (2x2 waves, 64x64/wave).
// LDS tiles [128][64] bf16 with XOR swizzle (row&7)<<4 on byte offset.
// ---------------------------------------------------------------------------
template <bool AF32, bool OUTBF16>
__global__ __launch_bounds__(256, 2)
void gemm_bt(const void* __restrict__ Ap, const float* __restrict__ Bp,
             void* __restrict__ Outp, int M, int N, int K)
{
  __shared__ __align__(16) char smA[128 * 128];  // 128 rows x 64 bf16 = 128B/row
  __shared__ __align__(16) char smB[128 * 128];
  const int tid = threadIdx.x;
  const int wid = tid >> 6, lane = tid & 63;
  const int wr = wid >> 1, wc = wid & 1;
  const int lg = lane >> 4, lr = lane & 15;
  const int m0 = blockIdx.y * 128, n0 = blockIdx.x * 128;

  const f32x4 z4 = {0.f, 0.f, 0.f, 0.f};
  f32x4 acc[4][4];
#pragma unroll
  for (int i = 0; i < 4; ++i)
#pragma unroll
    for (int j = 0; j < 4; ++j) acc[i][j] = z4;

  for (int k0 = 0; k0 < K; k0 += 64) {
    __syncthreads();
    // stage A tile (f32->bf16 convert or raw bf16), swizzled ds_write_b128
#pragma unroll
    for (int r2 = 0; r2 < 4; ++r2) {
      const int e = (r2 * 256 + tid) * 8;
      const int row = e >> 6, col = e & 63;
      u16x8 v;
      if (AF32) {
        const float* src = (const float*)Ap + (size_t)(m0 + row) * K + k0 + col;
        const float4 a = *(const float4*)src;
        const float4 b = *(const float4*)(src + 4);
        v[0] = f2bf(a.x); v[1] = f2bf(a.y); v[2] = f2bf(a.z); v[3] = f2bf(a.w);
        v[4] = f2bf(b.x); v[5] = f2bf(b.y); v[6] = f2bf(b.z); v[7] = f2bf(b.w);
      } else {
        v = *(const u16x8*)((const unsigned short*)Ap + (size_t)(m0 + row) * K + k0 + col);
      }
      *(u16x8*)(smA + row * 128 + ((col * 2) ^ ((row & 7) << 4))) = v;
    }
    // stage B tile (always f32 weights -> bf16)
#pragma unroll
    for (int r2 = 0; r2 < 4; ++r2) {
      const int e = (r2 * 256 + tid) * 8;
      const int row = e >> 6, col = e & 63;
      const float* src = Bp + (size_t)(n0 + row) * K + k0 + col;
      const float4 a = *(const float4*)src;
      const float4 b = *(const float4*)(src + 4);
      u16x8 v;
      v[0] = f2bf(a.x); v[1] = f2bf(a.y); v[2] = f2bf(a.z); v[3] = f2bf(a.w);
      v[4] = f2bf(b.x); v[5] = f2bf(b.y); v[6] = f2bf(b.z); v[7] = f2bf(b.w);
      *(u16x8*)(smB + row * 128 + ((col * 2) ^ ((row & 7) << 4))) = v;
    }
    __syncthreads();
#pragma unroll
    for (int kk = 0; kk < 2; ++kk) {
      const int cb = (kk * 32 + lg * 8) * 2;
      bf16x8 af[4], bfr[4];
#pragma unroll
      for (int i = 0; i < 4; ++i) {
        const int row = wr * 64 + i * 16 + lr;
        af[i] = *(const bf16x8*)(smA + row * 128 + (cb ^ ((row & 7) << 4)));
      }
#pragma unroll
      for (int j = 0; j < 4; ++j) {
        const int row = wc * 64 + j * 16 + lr;
        bfr[j] = *(const bf16x8*)(smB + row * 128 + (cb ^ ((row & 7) << 4)));
      }
#pragma unroll
      for (int i = 0; i < 4; ++i)
#pragma unroll
        for (int j = 0; j < 4; ++j)
          acc[i][j] = __builtin_amdgcn_mfma_f32_16x16x32_bf16(af[i], bfr[j], acc[i][j], 0, 0, 0);
    }
  }

  // epilogue: C/D layout col=lane&15, row=(lane>>4)*4+reg  [m89-verified]
#pragma unroll
  for (int i = 0; i < 4; ++i)
#pragma unroll
    for (int j = 0; j < 4; ++j)
#pragma unroll
      for (int r = 0; r < 4; ++r) {
        const int row = m0 + wr * 64 + i * 16 + lg * 4 + r;
        const int col = n0 + wc * 64 + j * 16 + lr;
        const float val = acc[i][j][r];
        if (OUTBF16) ((unsigned short*)Outp)[(size_t)row * N + col] = f2bf(val);
        else         ((float*)Outp)[(size_t)row * N + col] = val;
      }
}

// ---------------------------------------------------------------------------
// Flash attention, causal, past_len=0.
// qkv: bf16 [B*T][6144], row = b*T+t, col = s*2048 + h*128 + d (s=0:q,1:k,2:v)
// out: bf16 [B*T][2048], col = h*128 + d
// Block: 256 thr (4 waves), one (b,h) x 64-row Q tile; K-tiles of 64.
// Wave w owns S rows w*16..w*16+15. Online softmax in f32; P via swizzled LDS.
// ---------------------------------------------------------------------------
__global__ __launch_bounds__(256, 2)
void attn_fwd(const unsigned short* __restrict__ qkv, unsigned short* __restrict__ outp)
{
  constexpr int T = 2048, ROWS = 6144;
  const int qt = blockIdx.x;            // 0..31 (q tile)
  const int bh = blockIdx.y;            // 0..31
  const int b = bh >> 4, h = bh & 15;
  const int q0 = qt * 64;
  const int tid = threadIdx.x;
  const int wid = tid >> 6, lane = tid & 63;
  const int lg = lane >> 4, lr = lane & 15;

  __shared__ __align__(16) char Ks[64 * 256];   // [64 keys][128 d] bf16, swizzled
  __shared__ __align__(16) char Vt[128 * 128];  // [128 d][64 keys] bf16, swizzled
  __shared__ __align__(16) char Ps[64 * 128];   // [64 q][64 keys]  bf16, swizzled

  // hoist Q fragments to registers (A-frag: row=lane&15, k=(lane>>4)*8+b)
  const size_t qrow = (size_t)(b * T + q0 + wid * 16 + lr) * ROWS + h * 128;
  bf16x8 qf[4];
#pragma unroll
  for (int kd = 0; kd < 4; ++kd)
    qf[kd] = __builtin_bit_cast(bf16x8, *(const u16x8*)(qkv + qrow + kd * 32 + lg * 8));

  const f32x4 z4 = {0.f, 0.f, 0.f, 0.f};
  f32x4 oacc[8];
#pragma unroll
  for (int jj = 0; jj < 8; ++jj) oacc[jj] = z4;
  float mrow[4] = {-1e30f, -1e30f, -1e30f, -1e30f};
  float lsum[4] = {0.f, 0.f, 0.f, 0.f};
  const float scale = 0.08838834764831845f;   // 1/sqrt(128)

  for (int kt = 0; kt <= qt; ++kt) {
    __syncthreads();   // previous tile's LDS reads complete
    const int kbase = b * T + kt * 64;
    // stage K tile: [64][128] bf16, swizzled, coalesced 16B loads
#pragma unroll
    for (int r2 = 0; r2 < 4; ++r2) {
      const int e = (r2 * 256 + tid) * 8;
      const int row = e >> 7, col = e & 127;
      u16x8 v = *(const u16x8*)(qkv + (size_t)(kbase + row) * ROWS + 2048 + h * 128 + col);
      *(u16x8*)(Ks + row * 256 + ((col * 2) ^ ((row & 7) << 4))) = v;
    }
    // stage V transposed: Vt[d][n]; strided u16 global reads (coalesced per row),
    // contiguous 16B LDS writes
    {
      const int d = tid & 127;
      const int nh = (tid >> 7) * 32;
#pragma unroll
      for (int g = 0; g < 4; ++g) {
        u16x8 v;
#pragma unroll
        for (int i = 0; i < 8; ++i)
          v[i] = qkv[(size_t)(kbase + nh + g * 8 + i) * ROWS + 4096 + h * 128 + d];
        *(u16x8*)(Vt + d * 128 + (((nh + g * 8) * 2) ^ ((d & 7) << 4))) = v;
      }
    }
    __syncthreads();

    // S = Q K^T  (B-frag of K^T == row-major read of K tile)
    f32x4 sf[4];
#pragma unroll
    for (int j = 0; j < 4; ++j) sf[j] = z4;
#pragma unroll
    for (int kd = 0; kd < 4; ++kd) {
      const int cb = (kd * 32 + lg * 8) * 2;
#pragma unroll
      for (int j = 0; j < 4; ++j) {
        const int row = j * 16 + lr;
        bf16x8 kf = *(const bf16x8*)(Ks + row * 256 + (cb ^ ((row & 7) << 4)));
        sf[j] = __builtin_amdgcn_mfma_f32_16x16x32_bf16(qf[kd], kf, sf[j], 0, 0, 0);
      }
    }
    // scale + causal mask (only diagonal tile needs masking)
    const bool diag = (kt == qt);
#pragma unroll
    for (int j = 0; j < 4; ++j)
#pragma unroll
      for (int r = 0; r < 4; ++r) {
        float s = sf[j][r] * scale;
        if (diag && (j * 16 + lr > wid * 16 + lg * 4 + r)) s = -1e30f;
        sf[j][r] = s;
      }
    // row max over 64 cols: 4 frags then 16-lane butterfly
    float pm[4];
#pragma unroll
    for (int r = 0; r < 4; ++r)
      pm[r] = fmaxf(fmaxf(sf[0][r], sf[1][r]), fmaxf(sf[2][r], sf[3][r]));
#pragma unroll
    for (int msk = 1; msk < 16; msk <<= 1)
#pragma unroll
      for (int r = 0; r < 4; ++r) pm[r] = fmaxf(pm[r], __shfl_xor(pm[r], msk));
    float alpha[4];
#pragma unroll
    for (int r = 0; r < 4; ++r) {
      const float mn = fmaxf(mrow[r], pm[r]);
      alpha[r] = __expf(mrow[r] - mn);
      mrow[r] = mn;
    }
    // P = exp(S - m), write bf16 to swizzled Ps (same-wave consumer only)
    float rs[4] = {0.f, 0.f, 0.f, 0.f};
#pragma unroll
    for (int j = 0; j < 4; ++j)
#pragma unroll
      for (int r = 0; r < 4; ++r) {
        const float p = __expf(sf[j][r] - mrow[r]);
        rs[r] += p;
        const int prow = wid * 16 + lg * 4 + r;
        const int pcol = j * 16 + lr;
        *(unsigned short*)(Ps + prow * 128 + ((pcol * 2) ^ ((prow & 7) << 4))) = f2bf(p);
      }
#pragma unroll
    for (int msk = 1; msk < 16; msk <<= 1)
#pragma unroll
      for (int r = 0; r < 4; ++r) rs[r] += __shfl_xor(rs[r], msk);
#pragma unroll
    for (int r = 0; r < 4; ++r) lsum[r] = lsum[r] * alpha[r] + rs[r];
    // rescale O
#pragma unroll
    for (int jj = 0; jj < 8; ++jj)
#pragma unroll
      for (int r = 0; r < 4; ++r) oacc[jj][r] *= alpha[r];
    // same-wave DS ordering: drain P writes before P reads
    asm volatile("s_waitcnt lgkmcnt(0)" ::: "memory");
    // O += P V   (A-frag from Ps, B-frag from Vt)
#pragma unroll
    for (int kk = 0; kk < 2; ++kk) {
      const int prow = wid * 16 + lr;
      const int pcb = (kk * 32 + lg * 8) * 2;
      bf16x8 pf = *(const bf16x8*)(Ps + prow * 128 + (pcb ^ ((prow & 7) << 4)));
#pragma unroll
      for (int jj = 0; jj < 8; ++jj) {
        const int vrow = jj * 16 + lr;
        bf16x8 vf = *(const bf16x8*)(Vt + vrow * 128 + (pcb ^ ((vrow & 7) << 4)));
        oacc[jj] = __builtin_amdgcn_mfma_f32_16x16x32_bf16(pf, vf, oacc[jj], 0, 0, 0);
      }
    }
  }

  // epilogue: out[b*T + q][h*128 + d] = O / l
#pragma unroll
  for (int jj = 0; jj < 8; ++jj)
#pragma unroll
    for (int r = 0; r < 4; ++r) {
      const int q = q0 + wid * 16 + lg * 4 + r;
      const int col = h * 128 + jj * 16 + lr;
      const float o = oacc[jj][r] / lsum[r];
      outp[(size_t)(b * T + q) * 2048 + col] = f2bf(o);
    }
}

// ---------------------------------------------------------------------------
extern "C" void kernel_launch(void* const* d_in, const int* in_sizes, int n_in,
                              void* d_out, int out_size, void* d_ws, size_t ws_size,
                              hipStream_t stream) {
  (void)in_sizes; (void)n_in; (void)out_size; (void)ws_size;
  const float* x     = (const float*)d_in[0];   // [2,2048,2048]
  const float* qkvw  = (const float*)d_in[1];   // [6144,2048]
  const float* projw = (const float*)d_in[2];   // [2048,2048]
  // d_in[3] = past (all zeros, fully overwritten range -> unused)
  // d_in[4] = past_len (0)

  unsigned short* qkvb  = (unsigned short*)d_ws;              // [4096][6144] bf16
  unsigned short* attnb = qkvb + (size_t)4096 * 6144;         // [4096][2048] bf16
  float* out = (float*)d_out;                                 // [4096][2048] f32

  // qkv projection: 4096 x 6144 x 2048
  gemm_bt<true, true><<<dim3(6144 / 128, 4096 / 128), 256, 0, stream>>>(
      x, qkvw, qkvb, 4096, 6144, 2048);
  // causal attention
  attn_fwd<<<dim3(32, 32), 256, 0, stream>>>(qkvb, attnb);
  // output projection: 4096 x 2048 x 2048
  gemm_bt<false, false><<<dim3(2048 / 128, 4096 / 128), 256, 0, stream>>>(
      attnb, projw, out, 4096, 2048, 2048);
}

// Round 2
// 454.558 us; speedup vs baseline: 1.3961x; 1.3961x over previous
//
#include <hip/hip_runtime.h>

typedef __bf16 bf16x8 __attribute__((ext_vector_type(8)));
typedef float f32x4 __attribute__((ext_vector_type(4)));
typedef unsigned short u16x8 __attribute__((ext_vector_type(8)));

__device__ __forceinline__ unsigned short f2bf(float f) {
  unsigned int u = __builtin_bit_cast(unsigned int, f);
  u += 0x7FFFu + ((u >> 16) & 1u);           // round-to-nearest-even
  return (unsigned short)(u >> 16);
}

// ---------------------------------------------------------------------------
// GEMM: out[m][n] = sum_k A[m][k] * B[n][k]   (unchanged from R0)
// ---------------------------------------------------------------------------
template <bool AF32, bool OUTBF16>
__global__ __launch_bounds__(256, 2)
void gemm_bt(const void* __restrict__ Ap, const float* __restrict__ Bp,
             void* __restrict__ Outp, int M, int N, int K)
{
  __shared__ __align__(16) char smA[128 * 128];
  __shared__ __align__(16) char smB[128 * 128];
  const int tid = threadIdx.x;
  const int wid = tid >> 6, lane = tid & 63;
  const int wr = wid >> 1, wc = wid & 1;
  const int lg = lane >> 4, lr = lane & 15;
  const int m0 = blockIdx.y * 128, n0 = blockIdx.x * 128;

  const f32x4 z4 = {0.f, 0.f, 0.f, 0.f};
  f32x4 acc[4][4];
#pragma unroll
  for (int i = 0; i < 4; ++i)
#pragma unroll
    for (int j = 0; j < 4; ++j) acc[i][j] = z4;

  for (int k0 = 0; k0 < K; k0 += 64) {
    __syncthreads();
#pragma unroll
    for (int r2 = 0; r2 < 4; ++r2) {
      const int e = (r2 * 256 + tid) * 8;
      const int row = e >> 6, col = e & 63;
      u16x8 v;
      if (AF32) {
        const float* src = (const float*)Ap + (size_t)(m0 + row) * K + k0 + col;
        const float4 a = *(const float4*)src;
        const float4 b = *(const float4*)(src + 4);
        v[0] = f2bf(a.x); v[1] = f2bf(a.y); v[2] = f2bf(a.z); v[3] = f2bf(a.w);
        v[4] = f2bf(b.x); v[5] = f2bf(b.y); v[6] = f2bf(b.z); v[7] = f2bf(b.w);
      } else {
        v = *(const u16x8*)((const unsigned short*)Ap + (size_t)(m0 + row) * K + k0 + col);
      }
      *(u16x8*)(smA + row * 128 + ((col * 2) ^ ((row & 7) << 4))) = v;
    }
#pragma unroll
    for (int r2 = 0; r2 < 4; ++r2) {
      const int e = (r2 * 256 + tid) * 8;
      const int row = e >> 6, col = e & 63;
      const float* src = Bp + (size_t)(n0 + row) * K + k0 + col;
      const float4 a = *(const float4*)src;
      const float4 b = *(const float4*)(src + 4);
      u16x8 v;
      v[0] = f2bf(a.x); v[1] = f2bf(a.y); v[2] = f2bf(a.z); v[3] = f2bf(a.w);
      v[4] = f2bf(b.x); v[5] = f2bf(b.y); v[6] = f2bf(b.z); v[7] = f2bf(b.w);
      *(u16x8*)(smB + row * 128 + ((col * 2) ^ ((row & 7) << 4))) = v;
    }
    __syncthreads();
#pragma unroll
    for (int kk = 0; kk < 2; ++kk) {
      const int cb = (kk * 32 + lg * 8) * 2;
      bf16x8 af[4], bfr[4];
#pragma unroll
      for (int i = 0; i < 4; ++i) {
        const int row = wr * 64 + i * 16 + lr;
        af[i] = *(const bf16x8*)(smA + row * 128 + (cb ^ ((row & 7) << 4)));
      }
#pragma unroll
      for (int j = 0; j < 4; ++j) {
        const int row = wc * 64 + j * 16 + lr;
        bfr[j] = *(const bf16x8*)(smB + row * 128 + (cb ^ ((row & 7) << 4)));
      }
#pragma unroll
      for (int i = 0; i < 4; ++i)
#pragma unroll
        for (int j = 0; j < 4; ++j)
          acc[i][j] = __builtin_amdgcn_mfma_f32_16x16x32_bf16(af[i], bfr[j], acc[i][j], 0, 0, 0);
    }
  }
#pragma unroll
  for (int i = 0; i < 4; ++i)
#pragma unroll
    for (int j = 0; j < 4; ++j)
#pragma unroll
      for (int r = 0; r < 4; ++r) {
        const int row = m0 + wr * 64 + i * 16 + lg * 4 + r;
        const int col = n0 + wc * 64 + j * 16 + lr;
        const float val = acc[i][j][r];
        if (OUTBF16) ((unsigned short*)Outp)[(size_t)row * N + col] = f2bf(val);
        else         ((float*)Outp)[(size_t)row * N + col] = val;
      }
}

// ---------------------------------------------------------------------------
// Flash attention v2: register-double-buffered staging (T14), LDS-based V
// transpose, Vrow/Ps overlay, 48KB LDS -> 3 blocks/CU, qt descending.
// qkv: bf16 [B*T][6144]; out: bf16 [B*T][2048].
// ---------------------------------------------------------------------------
__global__ __launch_bounds__(256)
void attn_fwd(const unsigned short* __restrict__ qkv, unsigned short* __restrict__ outp)
{
  constexpr int T = 2048, ROWS = 6144;
  const int qt = (int)gridDim.x - 1 - (int)blockIdx.x;  // heavy tiles first
  const int bh = blockIdx.y;
  const int b = bh >> 4, h = bh & 15;
  const int q0 = qt * 64;
  const int tid = threadIdx.x;
  const int wid = tid >> 6, lane = tid & 63;
  const int lg = lane >> 4, lr = lane & 15;

  __shared__ __align__(16) char Ks[64 * 256];   // [64 k][128 d] bf16, swizzled
  __shared__ __align__(16) char Vt[128 * 128];  // [128 d][64 k] bf16, swizzled
  __shared__ __align__(16) char Sc[64 * 256];   // Vrow [64][128] bf16 / Ps [64][64] bf16 overlay

  // staging coords (same for K and V): 4 rounds x u16x8
  const int se_row[4] = {((0 * 256 + tid) * 8) >> 7, ((1 * 256 + tid) * 8) >> 7,
                         ((2 * 256 + tid) * 8) >> 7, ((3 * 256 + tid) * 8) >> 7};
  const int se_col = (tid * 8) & 127;  // col is same for all rounds (256 thr * 8 = 2048 = 16 rows)

  // Q fragments hoisted to registers
  const size_t qrow = (size_t)(b * T + q0 + wid * 16 + lr) * ROWS + h * 128;
  bf16x8 qf[4];
#pragma unroll
  for (int kd = 0; kd < 4; ++kd)
    qf[kd] = __builtin_bit_cast(bf16x8, *(const u16x8*)(qkv + qrow + kd * 32 + lg * 8));

  const f32x4 z4 = {0.f, 0.f, 0.f, 0.f};
  f32x4 oacc[8];
#pragma unroll
  for (int jj = 0; jj < 8; ++jj) oacc[jj] = z4;
  float mrow[4] = {-1e30f, -1e30f, -1e30f, -1e30f};
  float lsum[4] = {0.f, 0.f, 0.f, 0.f};
  const float scale = 0.08838834764831845f;   // 1/sqrt(128)

  u16x8 kreg[4], vreg[4];
  // prefetch tile 0
  {
    const int kbase = b * T;
#pragma unroll
    for (int r = 0; r < 4; ++r) {
      const size_t g = (size_t)(kbase + se_row[r]) * ROWS + h * 128 + se_col;
      kreg[r] = *(const u16x8*)(qkv + g + 2048);
      vreg[r] = *(const u16x8*)(qkv + g + 4096);
    }
  }

  for (int kt = 0; kt <= qt; ++kt) {
    __syncthreads();   // previous tile's LDS reads complete
    // write staged regs -> Ks, Sc(Vrow)
#pragma unroll
    for (int r = 0; r < 4; ++r) {
      const int row = se_row[r];
      const int sw = (se_col * 2) ^ ((row & 7) << 4);
      *(u16x8*)(Ks + row * 256 + sw) = kreg[r];
      *(u16x8*)(Sc + row * 256 + sw) = vreg[r];
    }
    __syncthreads();   // staging visible
    // prefetch next tile into regs (completes under compute)
    if (kt < qt) {
      const int kbase = b * T + (kt + 1) * 64;
#pragma unroll
      for (int r = 0; r < 4; ++r) {
        const size_t g = (size_t)(kbase + se_row[r]) * ROWS + h * 128 + se_col;
        kreg[r] = *(const u16x8*)(qkv + g + 2048);
        vreg[r] = *(const u16x8*)(qkv + g + 4096);
      }
    }

    // S = Q K^T
    f32x4 sf[4];
#pragma unroll
    for (int j = 0; j < 4; ++j) sf[j] = z4;
#pragma unroll
    for (int kd = 0; kd < 4; ++kd) {
      const int cb = (kd * 32 + lg * 8) * 2;
#pragma unroll
      for (int j = 0; j < 4; ++j) {
        const int row = j * 16 + lr;
        bf16x8 kf = *(const bf16x8*)(Ks + row * 256 + (cb ^ ((row & 7) << 4)));
        sf[j] = __builtin_amdgcn_mfma_f32_16x16x32_bf16(qf[kd], kf, sf[j], 0, 0, 0);
      }
    }

    // transpose V: Sc(Vrow)[k][d] -> Vt[d][k] via scalar LDS reads (2-way = free)
#pragma unroll
    for (int r2 = 0; r2 < 4; ++r2) {
      const int chunk = r2 * 256 + tid;
      const int d = chunk & 127, k0 = (chunk >> 7) * 8;
      u16x8 v;
#pragma unroll
      for (int i = 0; i < 8; ++i)
        v[i] = *(const unsigned short*)(Sc + (k0 + i) * 256 + ((d * 2) ^ (((k0 + i) & 7) << 4)));
      *(u16x8*)(Vt + d * 128 + ((k0 * 2) ^ ((d & 7) << 4))) = v;
    }

    // softmax VALU (no LDS): scale, mask, row-max, alpha, exp, row-sum, rescale O
    const bool diag = (kt == qt);
#pragma unroll
    for (int j = 0; j < 4; ++j)
#pragma unroll
      for (int r = 0; r < 4; ++r) {
        float s = sf[j][r] * scale;
        if (diag && (j * 16 + lr > wid * 16 + lg * 4 + r)) s = -1e30f;
        sf[j][r] = s;
      }
    float pm[4];
#pragma unroll
    for (int r = 0; r < 4; ++r)
      pm[r] = fmaxf(fmaxf(sf[0][r], sf[1][r]), fmaxf(sf[2][r], sf[3][r]));
#pragma unroll
    for (int msk = 1; msk < 16; msk <<= 1)
#pragma unroll
      for (int r = 0; r < 4; ++r) pm[r] = fmaxf(pm[r], __shfl_xor(pm[r], msk));
    float alpha[4];
#pragma unroll
    for (int r = 0; r < 4; ++r) {
      const float mn = fmaxf(mrow[r], pm[r]);
      alpha[r] = __expf(mrow[r] - mn);
      mrow[r] = mn;
    }
    float rs[4] = {0.f, 0.f, 0.f, 0.f};
#pragma unroll
    for (int j = 0; j < 4; ++j)
#pragma unroll
      for (int r = 0; r < 4; ++r) {
        const float p = __expf(sf[j][r] - mrow[r]);
        sf[j][r] = p;
        rs[r] += p;
      }
#pragma unroll
    for (int msk = 1; msk < 16; msk <<= 1)
#pragma unroll
      for (int r = 0; r < 4; ++r) rs[r] += __shfl_xor(rs[r], msk);
#pragma unroll
    for (int r = 0; r < 4; ++r) lsum[r] = lsum[r] * alpha[r] + rs[r];
#pragma unroll
    for (int jj = 0; jj < 8; ++jj)
#pragma unroll
      for (int r = 0; r < 4; ++r) oacc[jj][r] *= alpha[r];

    __syncthreads();   // Vt visible to all waves; Sc(Vrow) reads done -> Ps may reuse Sc

    // P -> Ps (Sc overlay), bf16 scalar writes (wave-private rows)
#pragma unroll
    for (int j = 0; j < 4; ++j)
#pragma unroll
      for (int r = 0; r < 4; ++r) {
        const int prow = wid * 16 + lg * 4 + r;
        const int pcol = j * 16 + lr;
        *(unsigned short*)(Sc + prow * 128 + ((pcol * 2) ^ ((prow & 7) << 4))) = f2bf(sf[j][r]);
      }
    // same-wave DS ordering: drain P writes before P reads (rule #18: +sched_barrier)
    asm volatile("s_waitcnt lgkmcnt(0)" ::: "memory");
    __builtin_amdgcn_sched_barrier(0);

    // O += P V
#pragma unroll
    for (int kk = 0; kk < 2; ++kk) {
      const int prow = wid * 16 + lr;
      const int pcb = (kk * 32 + lg * 8) * 2;
      bf16x8 pf = *(const bf16x8*)(Sc + prow * 128 + (pcb ^ ((prow & 7) << 4)));
#pragma unroll
      for (int jj = 0; jj < 8; ++jj) {
        const int vrow = jj * 16 + lr;
        bf16x8 vf = *(const bf16x8*)(Vt + vrow * 128 + (pcb ^ ((vrow & 7) << 4)));
        oacc[jj] = __builtin_amdgcn_mfma_f32_16x16x32_bf16(pf, vf, oacc[jj], 0, 0, 0);
      }
    }
  }

  // epilogue
#pragma unroll
  for (int jj = 0; jj < 8; ++jj)
#pragma unroll
    for (int r = 0; r < 4; ++r) {
      const int q = q0 + wid * 16 + lg * 4 + r;
      const int col = h * 128 + jj * 16 + lr;
      const float o = oacc[jj][r] / lsum[r];
      outp[(size_t)(b * T + q) * 2048 + col] = f2bf(o);
    }
}

// ---------------------------------------------------------------------------
extern "C" void kernel_launch(void* const* d_in, const int* in_sizes, int n_in,
                              void* d_out, int out_size, void* d_ws, size_t ws_size,
                              hipStream_t stream) {
  (void)in_sizes; (void)n_in; (void)out_size; (void)ws_size;
  const float* x     = (const float*)d_in[0];   // [2,2048,2048]
  const float* qkvw  = (const float*)d_in[1];   // [6144,2048]
  const float* projw = (const float*)d_in[2];   // [2048,2048]

  unsigned short* qkvb  = (unsigned short*)d_ws;              // [4096][6144] bf16
  unsigned short* attnb = qkvb + (size_t)4096 * 6144;         // [4096][2048] bf16
  float* out = (float*)d_out;                                 // [4096][2048] f32

  gemm_bt<true, true><<<dim3(6144 / 128, 4096 / 128), 256, 0, stream>>>(
      x, qkvw, qkvb, 4096, 6144, 2048);
  attn_fwd<<<dim3(32, 32), 256, 0, stream>>>(qkvb, attnb);
  gemm_bt<false, false><<<dim3(2048 / 128, 4096 / 128), 256, 0, stream>>>(
      attnb, projw, out, 4096, 2048, 2048);
}

// Round 3
// 351.813 us; speedup vs baseline: 1.8038x; 1.2920x over previous
//
#include <hip/hip_runtime.h>

typedef __bf16 bf16x8 __attribute__((ext_vector_type(8)));
typedef float f32x4 __attribute__((ext_vector_type(4)));
typedef unsigned short u16x8 __attribute__((ext_vector_type(8)));

__device__ __forceinline__ unsigned short f2bf(float f) {
  unsigned int u = __builtin_bit_cast(unsigned int, f);
  u += 0x7FFFu + ((u >> 16) & 1u);           // round-to-nearest-even
  return (unsigned short)(u >> 16);
}

__device__ __forceinline__ void gload16(const void* g, void* l) {
  __builtin_amdgcn_global_load_lds((const __attribute__((address_space(1))) unsigned int*)g,
                                   (__attribute__((address_space(3))) unsigned int*)l,
                                   16, 0, 0);
}

// ---------------------------------------------------------------------------
// f32 -> bf16 conversion for {x, qkv_w, proj_w}, one dispatch, block-routed.
// 2048 elems / block (256 thr x 8).
// ---------------------------------------------------------------------------
__global__ __launch_bounds__(256)
void cvt3_f32_bf16(const float* __restrict__ s0, unsigned short* __restrict__ d0, int n0,
                   const float* __restrict__ s1, unsigned short* __restrict__ d1, int n1,
                   const float* __restrict__ s2, unsigned short* __restrict__ d2)
{
  int blk = blockIdx.x;
  const float* s; unsigned short* d;
  if (blk < n0)            { s = s0; d = d0; }
  else if (blk < n0 + n1)  { s = s1; d = d1; blk -= n0; }
  else                     { s = s2; d = d2; blk -= n0 + n1; }
  const size_t e = ((size_t)blk * 256 + threadIdx.x) * 8;
  const float4 a = *(const float4*)(s + e);
  const float4 b = *(const float4*)(s + e + 4);
  u16x8 v;
  v[0] = f2bf(a.x); v[1] = f2bf(a.y); v[2] = f2bf(a.z); v[3] = f2bf(a.w);
  v[4] = f2bf(b.x); v[5] = f2bf(b.y); v[6] = f2bf(b.z); v[7] = f2bf(b.w);
  *(u16x8*)(d + e) = v;
}

// ---------------------------------------------------------------------------
// GEMM (m97 structure): out[m][n] = sum_k A[m][k]*B[n][k], A,B bf16 [.][K]
// row-major. 128x128 tile, BK=64, 256 thr (2x2 waves, 64x64/wave).
// Staging: width-16 global_load_lds, LINEAR LDS dest + inverse-swizzled
// global source (rule #21); reads use byte^((row&7)<<4) XOR swizzle.
// ---------------------------------------------------------------------------
template <bool OUTBF16>
__global__ __launch_bounds__(256, 2)
void gemm_bt16(const unsigned short* __restrict__ Ap, const unsigned short* __restrict__ Bp,
               void* __restrict__ Outp, int M, int N, int K)
{
  __shared__ __align__(16) char smA[128 * 128];  // 128 rows x 64 bf16 (128B/row), 16KB
  __shared__ __align__(16) char smB[128 * 128];
  const int tid = threadIdx.x;
  const int wid = tid >> 6, lane = tid & 63;
  const int wr = wid >> 1, wc = wid & 1;
  const int lg = lane >> 4, lr = lane & 15;
  const int m0 = blockIdx.y * 128, n0 = blockIdx.x * 128;

  // staging coords: chunk c covers rows c*32 + wid*8 + (lane>>3), this lane's
  // 16B slot holds global cols starting ((lane&7)^(lane>>3))*8 (XOR involution)
  const int srow = wid * 8 + (lane >> 3);                 // + c*32 per chunk
  const int scol = (((lane & 7) ^ (lane >> 3)) << 3);     // element col in tile
  const int lbase = wid * 1024;                           // wave-uniform LDS base per chunk

  const f32x4 z4 = {0.f, 0.f, 0.f, 0.f};
  f32x4 acc[4][4];
#pragma unroll
  for (int i = 0; i < 4; ++i)
#pragma unroll
    for (int j = 0; j < 4; ++j) acc[i][j] = z4;

  for (int k0 = 0; k0 < K; k0 += 64) {
    __syncthreads();                       // prior tile's LDS reads complete
#pragma unroll
    for (int c = 0; c < 4; ++c) {
      const int row = c * 32 + srow;
      gload16(Ap + (size_t)(m0 + row) * K + k0 + scol, smA + c * 4096 + lbase);
      gload16(Bp + (size_t)(n0 + row) * K + k0 + scol, smB + c * 4096 + lbase);
    }
    __syncthreads();                       // compiler drains vmcnt before barrier
#pragma unroll
    for (int kk = 0; kk < 2; ++kk) {
      const int cb = (kk * 32 + lg * 8) * 2;
      bf16x8 af[4], bfr[4];
#pragma unroll
      for (int i = 0; i < 4; ++i) {
        const int row = wr * 64 + i * 16 + lr;
        af[i] = *(const bf16x8*)(smA + row * 128 + (cb ^ ((row & 7) << 4)));
      }
#pragma unroll
      for (int j = 0; j < 4; ++j) {
        const int row = wc * 64 + j * 16 + lr;
        bfr[j] = *(const bf16x8*)(smB + row * 128 + (cb ^ ((row & 7) << 4)));
      }
#pragma unroll
      for (int i = 0; i < 4; ++i)
#pragma unroll
        for (int j = 0; j < 4; ++j)
          acc[i][j] = __builtin_amdgcn_mfma_f32_16x16x32_bf16(af[i], bfr[j], acc[i][j], 0, 0, 0);
    }
  }
  // epilogue: C/D layout col=lane&15, row=(lane>>4)*4+reg  [m89-verified]
#pragma unroll
  for (int i = 0; i < 4; ++i)
#pragma unroll
    for (int j = 0; j < 4; ++j)
#pragma unroll
      for (int r = 0; r < 4; ++r) {
        const int row = m0 + wr * 64 + i * 16 + lg * 4 + r;
        const int col = n0 + wc * 64 + j * 16 + lr;
        const float val = acc[i][j][r];
        if (OUTBF16) ((unsigned short*)Outp)[(size_t)row * N + col] = f2bf(val);
        else         ((float*)Outp)[(size_t)row * N + col] = val;
      }
}

// ---------------------------------------------------------------------------
// Flash attention (unchanged from R1): reg-double-buffered staging, LDS V
// transpose, Vrow/Ps overlay, qt descending.
// ---------------------------------------------------------------------------
__global__ __launch_bounds__(256)
void attn_fwd(const unsigned short* __restrict__ qkv, unsigned short* __restrict__ outp)
{
  constexpr int T = 2048, ROWS = 6144;
  const int qt = (int)gridDim.x - 1 - (int)blockIdx.x;
  const int bh = blockIdx.y;
  const int b = bh >> 4, h = bh & 15;
  const int q0 = qt * 64;
  const int tid = threadIdx.x;
  const int wid = tid >> 6, lane = tid & 63;
  const int lg = lane >> 4, lr = lane & 15;

  __shared__ __align__(16) char Ks[64 * 256];
  __shared__ __align__(16) char Vt[128 * 128];
  __shared__ __align__(16) char Sc[64 * 256];

  const int se_row[4] = {((0 * 256 + tid) * 8) >> 7, ((1 * 256 + tid) * 8) >> 7,
                         ((2 * 256 + tid) * 8) >> 7, ((3 * 256 + tid) * 8) >> 7};
  const int se_col = (tid * 8) & 127;

  const size_t qrow = (size_t)(b * T + q0 + wid * 16 + lr) * ROWS + h * 128;
  bf16x8 qf[4];
#pragma unroll
  for (int kd = 0; kd < 4; ++kd)
    qf[kd] = __builtin_bit_cast(bf16x8, *(const u16x8*)(qkv + qrow + kd * 32 + lg * 8));

  const f32x4 z4 = {0.f, 0.f, 0.f, 0.f};
  f32x4 oacc[8];
#pragma unroll
  for (int jj = 0; jj < 8; ++jj) oacc[jj] = z4;
  float mrow[4] = {-1e30f, -1e30f, -1e30f, -1e30f};
  float lsum[4] = {0.f, 0.f, 0.f, 0.f};
  const float scale = 0.08838834764831845f;

  u16x8 kreg[4], vreg[4];
  {
    const int kbase = b * T;
#pragma unroll
    for (int r = 0; r < 4; ++r) {
      const size_t g = (size_t)(kbase + se_row[r]) * ROWS + h * 128 + se_col;
      kreg[r] = *(const u16x8*)(qkv + g + 2048);
      vreg[r] = *(const u16x8*)(qkv + g + 4096);
    }
  }

  for (int kt = 0; kt <= qt; ++kt) {
    __syncthreads();
#pragma unroll
    for (int r = 0; r < 4; ++r) {
      const int row = se_row[r];
      const int sw = (se_col * 2) ^ ((row & 7) << 4);
      *(u16x8*)(Ks + row * 256 + sw) = kreg[r];
      *(u16x8*)(Sc + row * 256 + sw) = vreg[r];
    }
    __syncthreads();
    if (kt < qt) {
      const int kbase = b * T + (kt + 1) * 64;
#pragma unroll
      for (int r = 0; r < 4; ++r) {
        const size_t g = (size_t)(kbase + se_row[r]) * ROWS + h * 128 + se_col;
        kreg[r] = *(const u16x8*)(qkv + g + 2048);
        vreg[r] = *(const u16x8*)(qkv + g + 4096);
      }
    }

    f32x4 sf[4];
#pragma unroll
    for (int j = 0; j < 4; ++j) sf[j] = z4;
#pragma unroll
    for (int kd = 0; kd < 4; ++kd) {
      const int cb = (kd * 32 + lg * 8) * 2;
#pragma unroll
      for (int j = 0; j < 4; ++j) {
        const int row = j * 16 + lr;
        bf16x8 kf = *(const bf16x8*)(Ks + row * 256 + (cb ^ ((row & 7) << 4)));
        sf[j] = __builtin_amdgcn_mfma_f32_16x16x32_bf16(qf[kd], kf, sf[j], 0, 0, 0);
      }
    }

#pragma unroll
    for (int r2 = 0; r2 < 4; ++r2) {
      const int chunk = r2 * 256 + tid;
      const int d = chunk & 127, k0 = (chunk >> 7) * 8;
      u16x8 v;
#pragma unroll
      for (int i = 0; i < 8; ++i)
        v[i] = *(const unsigned short*)(Sc + (k0 + i) * 256 + ((d * 2) ^ (((k0 + i) & 7) << 4)));
      *(u16x8*)(Vt + d * 128 + ((k0 * 2) ^ ((d & 7) << 4))) = v;
    }

    const bool diag = (kt == qt);
#pragma unroll
    for (int j = 0; j < 4; ++j)
#pragma unroll
      for (int r = 0; r < 4; ++r) {
        float s = sf[j][r] * scale;
        if (diag && (j * 16 + lr > wid * 16 + lg * 4 + r)) s = -1e30f;
        sf[j][r] = s;
      }
    float pm[4];
#pragma unroll
    for (int r = 0; r < 4; ++r)
      pm[r] = fmaxf(fmaxf(sf[0][r], sf[1][r]), fmaxf(sf[2][r], sf[3][r]));
#pragma unroll
    for (int msk = 1; msk < 16; msk <<= 1)
#pragma unroll
      for (int r = 0; r < 4; ++r) pm[r] = fmaxf(pm[r], __shfl_xor(pm[r], msk));
    float alpha[4];
#pragma unroll
    for (int r = 0; r < 4; ++r) {
      const float mn = fmaxf(mrow[r], pm[r]);
      alpha[r] = __expf(mrow[r] - mn);
      mrow[r] = mn;
    }
    float rs[4] = {0.f, 0.f, 0.f, 0.f};
#pragma unroll
    for (int j = 0; j < 4; ++j)
#pragma unroll
      for (int r = 0; r < 4; ++r) {
        const float p = __expf(sf[j][r] - mrow[r]);
        sf[j][r] = p;
        rs[r] += p;
      }
#pragma unroll
    for (int msk = 1; msk < 16; msk <<= 1)
#pragma unroll
      for (int r = 0; r < 4; ++r) rs[r] += __shfl_xor(rs[r], msk);
#pragma unroll
    for (int r = 0; r < 4; ++r) lsum[r] = lsum[r] * alpha[r] + rs[r];
#pragma unroll
    for (int jj = 0; jj < 8; ++jj)
#pragma unroll
      for (int r = 0; r < 4; ++r) oacc[jj][r] *= alpha[r];

    __syncthreads();

#pragma unroll
    for (int j = 0; j < 4; ++j)
#pragma unroll
      for (int r = 0; r < 4; ++r) {
        const int prow = wid * 16 + lg * 4 + r;
        const int pcol = j * 16 + lr;
        *(unsigned short*)(Sc + prow * 128 + ((pcol * 2) ^ ((prow & 7) << 4))) = f2bf(sf[j][r]);
      }
    asm volatile("s_waitcnt lgkmcnt(0)" ::: "memory");
    __builtin_amdgcn_sched_barrier(0);

#pragma unroll
    for (int kk = 0; kk < 2; ++kk) {
      const int prow = wid * 16 + lr;
      const int pcb = (kk * 32 + lg * 8) * 2;
      bf16x8 pf = *(const bf16x8*)(Sc + prow * 128 + (pcb ^ ((prow & 7) << 4)));
#pragma unroll
      for (int jj = 0; jj < 8; ++jj) {
        const int vrow = jj * 16 + lr;
        bf16x8 vf = *(const bf16x8*)(Vt + vrow * 128 + (pcb ^ ((vrow & 7) << 4)));
        oacc[jj] = __builtin_amdgcn_mfma_f32_16x16x32_bf16(pf, vf, oacc[jj], 0, 0, 0);
      }
    }
  }

#pragma unroll
  for (int jj = 0; jj < 8; ++jj)
#pragma unroll
    for (int r = 0; r < 4; ++r) {
      const int q = q0 + wid * 16 + lg * 4 + r;
      const int col = h * 128 + jj * 16 + lr;
      const float o = oacc[jj][r] / lsum[r];
      outp[(size_t)(b * T + q) * 2048 + col] = f2bf(o);
    }
}

// ---------------------------------------------------------------------------
extern "C" void kernel_launch(void* const* d_in, const int* in_sizes, int n_in,
                              void* d_out, int out_size, void* d_ws, size_t ws_size,
                              hipStream_t stream) {
  (void)in_sizes; (void)n_in; (void)out_size; (void)ws_size;
  const float* x     = (const float*)d_in[0];   // [2,2048,2048]
  const float* qkvw  = (const float*)d_in[1];   // [6144,2048]
  const float* projw = (const float*)d_in[2];   // [2048,2048]

  unsigned short* qkvb   = (unsigned short*)d_ws;               // [4096][6144]
  unsigned short* attnb  = qkvb   + (size_t)4096 * 6144;        // [4096][2048]
  unsigned short* xb     = attnb  + (size_t)4096 * 2048;        // [4096][2048]
  unsigned short* qkvwb  = xb     + (size_t)4096 * 2048;        // [6144][2048]
  unsigned short* projwb = qkvwb  + (size_t)6144 * 2048;        // [2048][2048]
  float* out = (float*)d_out;                                   // [4096][2048] f32

  // f32 -> bf16: x (4096 blk) + qkv_w (6144 blk) + proj_w (2048 blk)
  cvt3_f32_bf16<<<4096 + 6144 + 2048, 256, 0, stream>>>(
      x, xb, 4096, qkvw, qkvwb, 6144, projw, projwb);
  // qkv projection: 4096 x 6144 x 2048
  gemm_bt16<true><<<dim3(6144 / 128, 4096 / 128), 256, 0, stream>>>(
      xb, qkvwb, qkvb, 4096, 6144, 2048);
  // causal attention
  attn_fwd<<<dim3(32, 32), 256, 0, stream>>>(qkvb, attnb);
  // output projection: 4096 x 2048 x 2048
  gemm_bt16<false><<<dim3(2048 / 128, 4096 / 128), 256, 0, stream>>>(
      attnb, projwb, out, 4096, 2048, 2048);
}